// Round 1
// 554.402 us; speedup vs baseline: 1.2132x; 1.2132x over previous
//
#include <hip/hip_runtime.h>
#include <hip/hip_bf16.h>
#include <stdint.h>

#define HWSZ 16384
#define CCH 192
#define NB 8
#define NHEAD 4
#define DHEAD 48

typedef unsigned short u16;
typedef __bf16 bf16x8 __attribute__((ext_vector_type(8)));
typedef float f32x4 __attribute__((ext_vector_type(4)));
typedef short s16x8 __attribute__((ext_vector_type(8)));

__device__ __forceinline__ float b2f(u16 h){
  union { unsigned u; float f; } v; v.u = ((unsigned)h) << 16; return v.f;
}
__device__ __forceinline__ u16 f2b(float f){
  union { float f; unsigned u; } v; v.f = f;
  unsigned r = v.u + 0x7fffu + ((v.u >> 16) & 1u);
  return (u16)(r >> 16);
}

// ---------------------------------------------------------------------------
// K1: per-pixel LayerNorm over 192 channels (f32 in); writes normalized x
// TRANSPOSED as bf16 [b][hw][192] (K-contiguous rows for A*B^T MFMA GEMMs).
// v2: ILP-driven rewrite — float4 staging loads (12 in flight/thread),
// all-4-wave parallel stats, vectorized s16x8 stores. LDS 52.7KB -> 3 blk/CU.
// ---------------------------------------------------------------------------
__global__ __launch_bounds__(256) void k_ln_t(
    const float* __restrict__ x, const float* __restrict__ lnw,
    const float* __restrict__ lnb, u16* __restrict__ out)
{
  __shared__ float xs[CCH * 66];   // [c][px] f32 tile, pad 66 (50688 B)
  __shared__ float red[512];       // partials -> {mu[64], rstd[64], lw[192], lb[192]}
  int tid = threadIdx.x;
  int bx  = blockIdx.x;
  int b    = bx >> 8;
  int tile = bx & 255;
  int p0   = tile * 64;

  // issue lnw/lnb loads early (consumed in repack phase)
  float wl = 0.f, bl = 0.f;
  if (tid >= 64){
    int c = tid - 64;
    wl = lnw[c]; bl = lnb[c];
  }

  // Phase A: load 192x64 f32 tile, 12 independent float4 per thread
  {
    const float* xb = x + (size_t)b * CCH * HWSZ + p0;
    int cq = tid >> 4;           // 0..15 channel sub-index
    int q  = tid & 15;           // px quad
    float4 v[12];
    #pragma unroll
    for (int i = 0; i < 12; ++i){
      int c = i * 16 + cq;
      v[i] = *(const float4*)(xb + (size_t)c * HWSZ + q * 4);
    }
    #pragma unroll
    for (int i = 0; i < 12; ++i){
      int c = i * 16 + cq;
      float* dst = &xs[c * 66 + q * 4];   // 8B-aligned (264c + 16q)
      *(float2*)(dst)     = make_float2(v[i].x, v[i].y);
      *(float2*)(dst + 2) = make_float2(v[i].z, v[i].w);
    }
  }
  __syncthreads();

  // Phase B: parallel stats — wave w sums channels [48w, 48w+48), lane = px
  {
    int w = tid >> 6, l = tid & 63;
    float s = 0.f, ss = 0.f;
    #pragma unroll
    for (int j = 0; j < 48; ++j){
      float v = xs[(48 * w + j) * 66 + l];   // consecutive lanes -> consecutive banks
      s += v; ss += v * v;
    }
    red[w * 64 + l]       = s;
    red[256 + w * 64 + l] = ss;
  }
  __syncthreads();

  // Phase C: finalize per-pixel mu/rstd (64 threads), keep in regs
  float mu = 0.f, rs = 0.f;
  if (tid < 64){
    float s  = red[tid]       + red[64 + tid]  + red[128 + tid] + red[192 + tid];
    float ss = red[256 + tid] + red[320 + tid] + red[384 + tid] + red[448 + tid];
    mu = s * (1.f / CCH);
    float var = ss * (1.f / CCH) - mu * mu;
    rs = rsqrtf(var + 1e-5f);
  }
  __syncthreads();
  // repack red = {mu[0..63], rstd[64..127], lw[128..319], lb[320..511]}
  if (tid < 64){ red[tid] = mu; red[64 + tid] = rs; }
  else { int c = tid - 64; red[128 + c] = wl; red[320 + c] = bl; }
  __syncthreads();

  // Phase D: normalize + transposed bf16 store [px][192], s16x8 per write
  {
    u16* ob = out + ((size_t)b * HWSZ + p0) * CCH;
    int px = tid >> 2;          // 0..63
    int cb = tid & 3;
    float m = red[px];
    float r = red[64 + px];
    #pragma unroll
    for (int i = 0; i < 6; ++i){
      int c8 = cb + i * 4;      // 0..23
      int c0 = c8 * 8;
      s16x8 pk;
      #pragma unroll
      for (int j = 0; j < 8; ++j){
        int c = c0 + j;
        // bank = (16*(tid&3) + 2j + px) mod 32 -> 2 lanes/bank (free)
        float o = (xs[c * 66 + px] - m) * r * red[128 + c] + red[320 + c];
        pk[j] = (short)f2b(o);
      }
      *(s16x8*)(&ob[(size_t)px * CCH + c0]) = pk;
    }
  }
}

// ---------------------------------------------------------------------------
// K2: MFMA GEMM  Out[b][o][n] = sum_c A[o][c] * Bm[b][n][c]   (A*B^T)
// ---------------------------------------------------------------------------
template<int F32OUT>
__global__ __launch_bounds__(256, 2) void k_gemm(
    const float* __restrict__ A, const u16* __restrict__ Bm,
    void* __restrict__ Outv, const float* __restrict__ resid)
{
  __shared__ u16 lA[64 * 200];
  __shared__ u16 lB[128 * 200];
  int tid = threadIdx.x;
  int n0 = blockIdx.x * 128;
  int m0 = blockIdx.y * 64;
  int b  = blockIdx.z;
  {
    const float* ap = A + m0 * CCH;
    #pragma unroll
    for (int i = 0; i < 6; ++i){
      int off = (i * 256 + tid) * 8;
      float4 v0 = *(const float4*)(ap + off);
      float4 v1 = *(const float4*)(ap + off + 4);
      int row = off / CCH, col = off - row * CCH;
      s16x8 pk;
      pk[0] = (short)f2b(v0.x); pk[1] = (short)f2b(v0.y);
      pk[2] = (short)f2b(v0.z); pk[3] = (short)f2b(v0.w);
      pk[4] = (short)f2b(v1.x); pk[5] = (short)f2b(v1.y);
      pk[6] = (short)f2b(v1.z); pk[7] = (short)f2b(v1.w);
      *(s16x8*)(&lA[row * 200 + col]) = pk;
    }
  }
  {
    const u16* bp = Bm + ((size_t)b * HWSZ + n0) * CCH;
    #pragma unroll
    for (int i = 0; i < 12; ++i){
      int off = (i * 256 + tid) * 8;
      int4 v = *(const int4*)(bp + off);
      int row = off / CCH, col = off - row * CCH;
      *(int4*)(&lB[row * 200 + col]) = v;
    }
  }
  __syncthreads();
  int lane = tid & 63, wid = tid >> 6;
  int quad = lane >> 4, r = lane & 15;
  int wm = (wid >> 1) * 32, wn = (wid & 1) * 64;
  f32x4 acc[2][4] = {};
  #pragma unroll
  for (int k0 = 0; k0 < CCH; k0 += 32){
    bf16x8 af[2], bfr[4];
    #pragma unroll
    for (int i = 0; i < 2; ++i)
      af[i] = *(const bf16x8*)(&lA[(wm + i * 16 + r) * 200 + k0 + quad * 8]);
    #pragma unroll
    for (int j = 0; j < 4; ++j)
      bfr[j] = *(const bf16x8*)(&lB[(wn + j * 16 + r) * 200 + k0 + quad * 8]);
    #pragma unroll
    for (int i = 0; i < 2; ++i)
      #pragma unroll
      for (int j = 0; j < 4; ++j)
        acc[i][j] = __builtin_amdgcn_mfma_f32_16x16x32_bf16(af[i], bfr[j], acc[i][j], 0, 0, 0);
  }
  size_t obase = (size_t)b * CCH * HWSZ;
  #pragma unroll
  for (int i = 0; i < 2; ++i){
    #pragma unroll
    for (int rg = 0; rg < 4; ++rg){
      int o = m0 + wm + i * 16 + quad * 4 + rg;
      size_t rowb = obase + (size_t)o * HWSZ;
      #pragma unroll
      for (int j = 0; j < 4; ++j){
        int n = n0 + wn + j * 16 + r;
        float vv = acc[i][j][rg];
        if (F32OUT){
          ((float*)Outv)[rowb + n] = vv + resid[rowb + n];
        } else {
          ((u16*)Outv)[rowb + n] = f2b(vv);
        }
      }
    }
  }
}

// ---------------------------------------------------------------------------
// K3: merged depthwise 3x3 for q,k,v — one block = one full 128x128 plane,
// staged in LDS, computed IN-PLACE (8 px per thread, vectorized).
// blockIdx.y: 0=q (ssq_q), 1=k (ssq_k), 2=v (no ssq).
// ---------------------------------------------------------------------------
__global__ __launch_bounds__(256) void k_dw3(
    const float* __restrict__ wq, const float* __restrict__ wk,
    const float* __restrict__ wv,
    u16* __restrict__ bq, u16* __restrict__ bk, u16* __restrict__ bv,
    float* __restrict__ ssq_q, float* __restrict__ ssq_k)
{
  __shared__ u16 pln[HWSZ];             // 32 KB
  int tid = threadIdx.x;
  int bc  = blockIdx.x;                 // b*192 + c
  int z   = blockIdx.y;                 // 0=q 1=k 2=v
  int c   = bc % CCH;
  const float* wd = (z == 0) ? wq : (z == 1) ? wk : wv;
  u16* buf = (z == 0) ? bq : (z == 1) ? bk : bv;
  float w[9];
  #pragma unroll
  for (int t = 0; t < 9; ++t) w[t] = wd[c * 9 + t];
  u16* p = buf + (size_t)bc * HWSZ;
  // stage full plane into LDS (coalesced int4)
  {
    int4* lp = (int4*)pln;
    const int4* gp = (const int4*)p;
    #pragma unroll
    for (int i = 0; i < 8; ++i) lp[i * 256 + tid] = gp[i * 256 + tid];
  }
  __syncthreads();
  float ss = 0.f;
  #pragma unroll
  for (int i = 0; i < 8; ++i){
    int s  = i * 256 + tid;             // 2048 segments of 8 px
    int y  = s >> 4;
    int x0 = (s & 15) << 3;
    float acc[8] = {0.f,0.f,0.f,0.f,0.f,0.f,0.f,0.f};
    #pragma unroll
    for (int dy = 0; dy < 3; ++dy){
      int yy = y + dy - 1;
      if (yy < 0 || yy > 127) continue;
      int base = yy * 128 + x0;
      s16x8 cv = *(const s16x8*)(&pln[base]);
      float c8[8];
      #pragma unroll
      for (int j = 0; j < 8; ++j) c8[j] = b2f((u16)cv[j]);
      float lft = (x0 > 0)   ? b2f(pln[base - 1]) : 0.f;
      float rgt = (x0 < 120) ? b2f(pln[base + 8]) : 0.f;
      float wl = w[dy * 3], wc = w[dy * 3 + 1], wr = w[dy * 3 + 2];
      acc[0] += wl * lft + wc * c8[0] + wr * c8[1];
      #pragma unroll
      for (int j = 1; j < 7; ++j)
        acc[j] += wl * c8[j - 1] + wc * c8[j] + wr * c8[j + 1];
      acc[7] += wl * c8[6] + wc * c8[7] + wr * rgt;
    }
    s16x8 pk;
    #pragma unroll
    for (int j = 0; j < 8; ++j){
      pk[j] = (short)f2b(acc[j]);
      ss += acc[j] * acc[j];
    }
    *(s16x8*)(p + y * 128 + x0) = pk;   // in-place write (reads were from LDS)
  }
  if (z < 2){
    #pragma unroll
    for (int m = 32; m > 0; m >>= 1) ss += __shfl_xor(ss, m);
    if ((tid & 63) == 0) atomicAdd(&((z == 0) ? ssq_q : ssq_k)[bc], ss);
  }
}

// ---------------------------------------------------------------------------
// K4: raw gram G[b][h][c][d] += sum_n q[c,n]*k[d,n], split-K (16 chunks),
// MFMA fragments straight from global, atomicAdd out.
// ---------------------------------------------------------------------------
__global__ void k_gram(const u16* __restrict__ q, const u16* __restrict__ k,
                       float* __restrict__ G)
{
  int tid = threadIdx.x;
  int chunk = blockIdx.x;
  int h = blockIdx.y, b = blockIdx.z;
  int lane = tid & 63, w = tid >> 6;
  int quad = lane >> 4, r = lane & 15;
  int nb = chunk * 1024 + w * 256;
  const u16* qb = q + ((size_t)b * CCH + h * DHEAD) * HWSZ;
  const u16* kb = k + ((size_t)b * CCH + h * DHEAD) * HWSZ;
  f32x4 acc[3][3] = {};
  for (int s = 0; s < 8; ++s){
    int kk = nb + s * 32 + quad * 8;
    bf16x8 af[3], bfr[3];
    #pragma unroll
    for (int i = 0; i < 3; ++i){
      af[i]  = *(const bf16x8*)(qb + (size_t)(i * 16 + r) * HWSZ + kk);
      bfr[i] = *(const bf16x8*)(kb + (size_t)(i * 16 + r) * HWSZ + kk);
    }
    #pragma unroll
    for (int i = 0; i < 3; ++i)
      #pragma unroll
      for (int j = 0; j < 3; ++j)
        acc[i][j] = __builtin_amdgcn_mfma_f32_16x16x32_bf16(af[i], bfr[j], acc[i][j], 0, 0, 0);
  }
  float* gb = G + (size_t)(b * NHEAD + h) * (DHEAD * DHEAD);
  #pragma unroll
  for (int i = 0; i < 3; ++i)
    #pragma unroll
    for (int j = 0; j < 3; ++j)
      #pragma unroll
      for (int rg = 0; rg < 4; ++rg){
        int row = i * 16 + quad * 4 + rg;
        int col = j * 16 + r;
        atomicAdd(&gb[row * DHEAD + col], acc[i][j][rg]);
      }
}

// ---------------------------------------------------------------------------
// K5: fused (1/||q||,1/||k||,temp) -> softmax -> attn@V; writes attention
// output TRANSPOSED bf16 [b][n][192] (K-contiguous for proj GEMM).
// ---------------------------------------------------------------------------
__global__ void k_attnv(const float* __restrict__ G, const float* __restrict__ ssq_q,
                        const float* __restrict__ ssq_k, const float* __restrict__ temp,
                        const u16* __restrict__ v, u16* __restrict__ aot)
{
  __shared__ float at[DHEAD * 49];
  __shared__ float rqs[DHEAD], rks[DHEAD];
  int tid = threadIdx.x;
  int chunk = blockIdx.x;
  int h = blockIdx.y, b = blockIdx.z;
  const float* gb = G + (size_t)(b * NHEAD + h) * (DHEAD * DHEAD);
  #pragma unroll
  for (int i = 0; i < 9; ++i){
    int e = i * 256 + tid;
    int rw = e / DHEAD;
    at[rw * 49 + (e - rw * DHEAD)] = gb[e];
  }
  if (tid < DHEAD){
    float sq = sqrtf(ssq_q[b * CCH + h * DHEAD + tid]);
    float sk = sqrtf(ssq_k[b * CCH + h * DHEAD + tid]);
    rqs[tid] = 1.f / fmaxf(sq, 1e-12f);
    rks[tid] = 1.f / fmaxf(sk, 1e-12f);
  }
  __syncthreads();
  if (tid < DHEAD){
    float rq = rqs[tid] * temp[h];
    float mx = -1e30f;
    #pragma unroll
    for (int d = 0; d < DHEAD; ++d){
      float a = at[tid * 49 + d] * rq * rks[d];
      at[tid * 49 + d] = a;
      mx = fmaxf(mx, a);
    }
    float sum = 0.f;
    #pragma unroll
    for (int d = 0; d < DHEAD; ++d){
      float e = __expf(at[tid * 49 + d] - mx);
      at[tid * 49 + d] = e;
      sum += e;
    }
    float inv = 1.f / sum;
    #pragma unroll
    for (int d = 0; d < DHEAD; ++d) at[tid * 49 + d] *= inv;
  }
  __syncthreads();
  int n = chunk * 256 + tid;
  const u16* vb = v + ((size_t)b * CCH + h * DHEAD) * HWSZ + n;
  float o[DHEAD];
  #pragma unroll
  for (int cdx = 0; cdx < DHEAD; ++cdx) o[cdx] = 0.f;
  for (int d = 0; d < DHEAD; ++d){
    float vv = b2f(vb[(size_t)d * HWSZ]);
    #pragma unroll
    for (int cdx = 0; cdx < DHEAD; ++cdx)
      o[cdx] += at[cdx * 49 + d] * vv;
  }
  u16* ab = aot + ((size_t)b * HWSZ + n) * CCH + h * DHEAD;
  #pragma unroll
  for (int g = 0; g < 6; ++g){
    s16x8 pk;
    #pragma unroll
    for (int e = 0; e < 8; ++e) pk[e] = (short)f2b(o[g * 8 + e]);
    *(s16x8*)(&ab[g * 8]) = pk;
  }
}

// ---------------------------------------------------------------------------
extern "C" void kernel_launch(void* const* d_in, const int* in_sizes, int n_in,
                              void* d_out, int out_size, void* d_ws, size_t ws_size,
                              hipStream_t stream)
{
  const float* xx     = (const float*)d_in[0];
  const float* q_in   = (const float*)d_in[1];
  const float* ln_w   = (const float*)d_in[2];
  const float* ln_b   = (const float*)d_in[3];
  const float* w_q    = (const float*)d_in[4];
  const float* w_k    = (const float*)d_in[5];
  const float* w_v    = (const float*)d_in[6];
  const float* wd_q   = (const float*)d_in[7];
  const float* wd_k   = (const float*)d_in[8];
  const float* wd_v   = (const float*)d_in[9];
  const float* w_proj = (const float*)d_in[10];
  const float* temp   = (const float*)d_in[11];

  const size_t SZ = (size_t)NB * CCH * HWSZ;
  u16* B1 = (u16*)d_ws;                          // xnT / qnT -> AOT
  u16* B2 = B1 + SZ;                             // k_conv -> k_dw (in-place)
  u16* B3 = B2 + SZ;                             // q_conv -> q_dw (in-place)
  float* G     = (float*)(B3 + SZ);
  float* ssq_q = G + 32 * DHEAD * DHEAD;
  float* ssq_k = ssq_q + NB * CCH;
  u16* outscratch = (u16*)d_out;                 // v_conv -> v_dw (in-place)

  hipMemsetAsync(G, 0, (size_t)(32 * DHEAD * DHEAD + 2 * NB * CCH) * sizeof(float), stream);

  dim3 gg(128, 3, NB);
  k_ln_t<<<NB * 256, 256, 0, stream>>>(xx, ln_w, ln_b, B1);
  k_gemm<0><<<gg, 256, 0, stream>>>(w_k, B1, B2, nullptr);
  k_gemm<0><<<gg, 256, 0, stream>>>(w_v, B1, outscratch, nullptr);
  k_ln_t<<<NB * 256, 256, 0, stream>>>(q_in, ln_w, ln_b, B1);
  k_gemm<0><<<gg, 256, 0, stream>>>(w_q, B1, B3, nullptr);
  // merged depthwise: q in B3, k in B2, v in outscratch — all in-place
  k_dw3<<<dim3(NB * CCH, 3), 256, 0, stream>>>(wd_q, wd_k, wd_v,
                                               B3, B2, outscratch, ssq_q, ssq_k);
  // gram (q_dw=B3, k_dw=B2) -> G ; softmax+attn@V (v=outscratch) -> AOT=B1
  k_gram<<<dim3(16, NHEAD, NB), 256, 0, stream>>>(B3, B2, G);
  k_attnv<<<dim3(64, NHEAD, NB), 256, 0, stream>>>(G, ssq_q, ssq_k, temp, outscratch, B1);
  // proj + residual -> d_out (f32)
  k_gemm<1><<<gg, 256, 0, stream>>>(w_proj, B1, d_out, q_in);
}

// Round 2
// 477.979 us; speedup vs baseline: 1.4072x; 1.1599x over previous
//
#include <hip/hip_runtime.h>
#include <hip/hip_bf16.h>
#include <stdint.h>

#define HWSZ 16384
#define CCH 192
#define NB 8
#define NHEAD 4
#define DHEAD 48

typedef unsigned short u16;
typedef __bf16 bf16x8 __attribute__((ext_vector_type(8)));
typedef float f32x4 __attribute__((ext_vector_type(4)));
typedef short s16x8 __attribute__((ext_vector_type(8)));
typedef short s16x4 __attribute__((ext_vector_type(4)));

__device__ __forceinline__ float b2f(u16 h){
  union { unsigned u; float f; } v; v.u = ((unsigned)h) << 16; return v.f;
}
__device__ __forceinline__ u16 f2b(float f){
  union { float f; unsigned u; } v; v.f = f;
  unsigned r = v.u + 0x7fffu + ((v.u >> 16) & 1u);
  return (u16)(r >> 16);
}

// ---------------------------------------------------------------------------
// K1: per-pixel LayerNorm over 192 channels (f32 in); writes normalized x
// TRANSPOSED as bf16 [b][hw][192] (K-contiguous rows for A*B^T MFMA GEMMs).
// ---------------------------------------------------------------------------
__global__ __launch_bounds__(256) void k_ln_t(
    const float* __restrict__ x, const float* __restrict__ lnw,
    const float* __restrict__ lnb, u16* __restrict__ out)
{
  __shared__ float xs[CCH * 66];   // [c][px] f32 tile, pad 66 (50688 B)
  __shared__ float red[512];       // partials -> {mu[64], rstd[64], lw[192], lb[192]}
  int tid = threadIdx.x;
  int bx  = blockIdx.x;
  int b    = bx >> 8;
  int tile = bx & 255;
  int p0   = tile * 64;

  float wl = 0.f, bl = 0.f;
  if (tid >= 64){
    int c = tid - 64;
    wl = lnw[c]; bl = lnb[c];
  }

  // Phase A: load 192x64 f32 tile, 12 independent float4 per thread
  {
    const float* xb = x + (size_t)b * CCH * HWSZ + p0;
    int cq = tid >> 4;           // 0..15 channel sub-index
    int q  = tid & 15;           // px quad
    float4 v[12];
    #pragma unroll
    for (int i = 0; i < 12; ++i){
      int c = i * 16 + cq;
      v[i] = *(const float4*)(xb + (size_t)c * HWSZ + q * 4);
    }
    #pragma unroll
    for (int i = 0; i < 12; ++i){
      int c = i * 16 + cq;
      float* dst = &xs[c * 66 + q * 4];
      *(float2*)(dst)     = make_float2(v[i].x, v[i].y);
      *(float2*)(dst + 2) = make_float2(v[i].z, v[i].w);
    }
  }
  __syncthreads();

  // Phase B: parallel stats — wave w sums channels [48w, 48w+48), lane = px
  {
    int w = tid >> 6, l = tid & 63;
    float s = 0.f, ss = 0.f;
    #pragma unroll
    for (int j = 0; j < 48; ++j){
      float v = xs[(48 * w + j) * 66 + l];
      s += v; ss += v * v;
    }
    red[w * 64 + l]       = s;
    red[256 + w * 64 + l] = ss;
  }
  __syncthreads();

  float mu = 0.f, rs = 0.f;
  if (tid < 64){
    float s  = red[tid]       + red[64 + tid]  + red[128 + tid] + red[192 + tid];
    float ss = red[256 + tid] + red[320 + tid] + red[384 + tid] + red[448 + tid];
    mu = s * (1.f / CCH);
    float var = ss * (1.f / CCH) - mu * mu;
    rs = rsqrtf(var + 1e-5f);
  }
  __syncthreads();
  if (tid < 64){ red[tid] = mu; red[64 + tid] = rs; }
  else { int c = tid - 64; red[128 + c] = wl; red[320 + c] = bl; }
  __syncthreads();

  // Phase D: normalize + transposed bf16 store [px][192], s16x8 per write
  {
    u16* ob = out + ((size_t)b * HWSZ + p0) * CCH;
    int px = tid >> 2;          // 0..63
    int cb = tid & 3;
    float m = red[px];
    float r = red[64 + px];
    #pragma unroll
    for (int i = 0; i < 6; ++i){
      int c8 = cb + i * 4;      // 0..23
      int c0 = c8 * 8;
      s16x8 pk;
      #pragma unroll
      for (int j = 0; j < 8; ++j){
        int c = c0 + j;
        float o = (xs[c * 66 + px] - m) * r * red[128 + c] + red[320 + c];
        pk[j] = (short)f2b(o);
      }
      *(s16x8*)(&ob[(size_t)px * CCH + c0]) = pk;
    }
  }
}

// ---------------------------------------------------------------------------
// K2: MFMA GEMM  Out[b][o][n] = sum_c A[o][c] * Bm[b][n][c]   (A*B^T)
// ---------------------------------------------------------------------------
template<int F32OUT>
__global__ __launch_bounds__(256, 2) void k_gemm(
    const float* __restrict__ A, const u16* __restrict__ Bm,
    void* __restrict__ Outv, const float* __restrict__ resid)
{
  __shared__ u16 lA[64 * 200];
  __shared__ u16 lB[128 * 200];
  int tid = threadIdx.x;
  int n0 = blockIdx.x * 128;
  int m0 = blockIdx.y * 64;
  int b  = blockIdx.z;
  {
    const float* ap = A + m0 * CCH;
    #pragma unroll
    for (int i = 0; i < 6; ++i){
      int off = (i * 256 + tid) * 8;
      float4 v0 = *(const float4*)(ap + off);
      float4 v1 = *(const float4*)(ap + off + 4);
      int row = off / CCH, col = off - row * CCH;
      s16x8 pk;
      pk[0] = (short)f2b(v0.x); pk[1] = (short)f2b(v0.y);
      pk[2] = (short)f2b(v0.z); pk[3] = (short)f2b(v0.w);
      pk[4] = (short)f2b(v1.x); pk[5] = (short)f2b(v1.y);
      pk[6] = (short)f2b(v1.z); pk[7] = (short)f2b(v1.w);
      *(s16x8*)(&lA[row * 200 + col]) = pk;
    }
  }
  {
    const u16* bp = Bm + ((size_t)b * HWSZ + n0) * CCH;
    #pragma unroll
    for (int i = 0; i < 12; ++i){
      int off = (i * 256 + tid) * 8;
      int4 v = *(const int4*)(bp + off);
      int row = off / CCH, col = off - row * CCH;
      *(int4*)(&lB[row * 200 + col]) = v;
    }
  }
  __syncthreads();
  int lane = tid & 63, wid = tid >> 6;
  int quad = lane >> 4, r = lane & 15;
  int wm = (wid >> 1) * 32, wn = (wid & 1) * 64;
  f32x4 acc[2][4] = {};
  #pragma unroll
  for (int k0 = 0; k0 < CCH; k0 += 32){
    bf16x8 af[2], bfr[4];
    #pragma unroll
    for (int i = 0; i < 2; ++i)
      af[i] = *(const bf16x8*)(&lA[(wm + i * 16 + r) * 200 + k0 + quad * 8]);
    #pragma unroll
    for (int j = 0; j < 4; ++j)
      bfr[j] = *(const bf16x8*)(&lB[(wn + j * 16 + r) * 200 + k0 + quad * 8]);
    #pragma unroll
    for (int i = 0; i < 2; ++i)
      #pragma unroll
      for (int j = 0; j < 4; ++j)
        acc[i][j] = __builtin_amdgcn_mfma_f32_16x16x32_bf16(af[i], bfr[j], acc[i][j], 0, 0, 0);
  }
  size_t obase = (size_t)b * CCH * HWSZ;
  #pragma unroll
  for (int i = 0; i < 2; ++i){
    #pragma unroll
    for (int rg = 0; rg < 4; ++rg){
      int o = m0 + wm + i * 16 + quad * 4 + rg;
      size_t rowb = obase + (size_t)o * HWSZ;
      #pragma unroll
      for (int j = 0; j < 4; ++j){
        int n = n0 + wn + j * 16 + r;
        float vv = acc[i][j][rg];
        if (F32OUT){
          ((float*)Outv)[rowb + n] = vv + resid[rowb + n];
        } else {
          ((u16*)Outv)[rowb + n] = f2b(vv);
        }
      }
    }
  }
}

// ---------------------------------------------------------------------------
// K3: merged depthwise 3x3 for q,k,v — one block = one full 128x128 plane,
// staged in LDS, computed IN-PLACE (8 px per thread, vectorized).
// ---------------------------------------------------------------------------
__global__ __launch_bounds__(256) void k_dw3(
    const float* __restrict__ wq, const float* __restrict__ wk,
    const float* __restrict__ wv,
    u16* __restrict__ bq, u16* __restrict__ bk, u16* __restrict__ bv,
    float* __restrict__ ssq_q, float* __restrict__ ssq_k)
{
  __shared__ u16 pln[HWSZ];             // 32 KB
  int tid = threadIdx.x;
  int bc  = blockIdx.x;                 // b*192 + c
  int z   = blockIdx.y;                 // 0=q 1=k 2=v
  int c   = bc % CCH;
  const float* wd = (z == 0) ? wq : (z == 1) ? wk : wv;
  u16* buf = (z == 0) ? bq : (z == 1) ? bk : bv;
  float w[9];
  #pragma unroll
  for (int t = 0; t < 9; ++t) w[t] = wd[c * 9 + t];
  u16* p = buf + (size_t)bc * HWSZ;
  {
    int4* lp = (int4*)pln;
    const int4* gp = (const int4*)p;
    #pragma unroll
    for (int i = 0; i < 8; ++i) lp[i * 256 + tid] = gp[i * 256 + tid];
  }
  __syncthreads();
  float ss = 0.f;
  #pragma unroll
  for (int i = 0; i < 8; ++i){
    int s  = i * 256 + tid;             // 2048 segments of 8 px
    int y  = s >> 4;
    int x0 = (s & 15) << 3;
    float acc[8] = {0.f,0.f,0.f,0.f,0.f,0.f,0.f,0.f};
    #pragma unroll
    for (int dy = 0; dy < 3; ++dy){
      int yy = y + dy - 1;
      if (yy < 0 || yy > 127) continue;
      int base = yy * 128 + x0;
      s16x8 cv = *(const s16x8*)(&pln[base]);
      float c8[8];
      #pragma unroll
      for (int j = 0; j < 8; ++j) c8[j] = b2f((u16)cv[j]);
      float lft = (x0 > 0)   ? b2f(pln[base - 1]) : 0.f;
      float rgt = (x0 < 120) ? b2f(pln[base + 8]) : 0.f;
      float wl = w[dy * 3], wc = w[dy * 3 + 1], wr = w[dy * 3 + 2];
      acc[0] += wl * lft + wc * c8[0] + wr * c8[1];
      #pragma unroll
      for (int j = 1; j < 7; ++j)
        acc[j] += wl * c8[j - 1] + wc * c8[j] + wr * c8[j + 1];
      acc[7] += wl * c8[6] + wc * c8[7] + wr * rgt;
    }
    s16x8 pk;
    #pragma unroll
    for (int j = 0; j < 8; ++j){
      pk[j] = (short)f2b(acc[j]);
      ss += acc[j] * acc[j];
    }
    *(s16x8*)(p + y * 128 + x0) = pk;
  }
  if (z < 2){
    #pragma unroll
    for (int m = 32; m > 0; m >>= 1) ss += __shfl_xor(ss, m);
    if ((tid & 63) == 0) atomicAdd(&((z == 0) ? ssq_q : ssq_k)[bc], ss);
  }
}

// ---------------------------------------------------------------------------
// K4: raw gram G[b][h][c][d] += sum_n q[c,n]*k[d,n], split-K (16 chunks),
// MFMA fragments straight from global, atomicAdd out.
// ---------------------------------------------------------------------------
__global__ void k_gram(const u16* __restrict__ q, const u16* __restrict__ k,
                       float* __restrict__ G)
{
  int tid = threadIdx.x;
  int chunk = blockIdx.x;
  int h = blockIdx.y, b = blockIdx.z;
  int lane = tid & 63, w = tid >> 6;
  int quad = lane >> 4, r = lane & 15;
  int nb = chunk * 1024 + w * 256;
  const u16* qb = q + ((size_t)b * CCH + h * DHEAD) * HWSZ;
  const u16* kb = k + ((size_t)b * CCH + h * DHEAD) * HWSZ;
  f32x4 acc[3][3] = {};
  for (int s = 0; s < 8; ++s){
    int kk = nb + s * 32 + quad * 8;
    bf16x8 af[3], bfr[3];
    #pragma unroll
    for (int i = 0; i < 3; ++i){
      af[i]  = *(const bf16x8*)(qb + (size_t)(i * 16 + r) * HWSZ + kk);
      bfr[i] = *(const bf16x8*)(kb + (size_t)(i * 16 + r) * HWSZ + kk);
    }
    #pragma unroll
    for (int i = 0; i < 3; ++i)
      #pragma unroll
      for (int j = 0; j < 3; ++j)
        acc[i][j] = __builtin_amdgcn_mfma_f32_16x16x32_bf16(af[i], bfr[j], acc[i][j], 0, 0, 0);
  }
  float* gb = G + (size_t)(b * NHEAD + h) * (DHEAD * DHEAD);
  #pragma unroll
  for (int i = 0; i < 3; ++i)
    #pragma unroll
    for (int j = 0; j < 3; ++j)
      #pragma unroll
      for (int rg = 0; rg < 4; ++rg){
        int row = i * 16 + quad * 4 + rg;
        int col = j * 16 + r;
        atomicAdd(&gb[row * DHEAD + col], acc[i][j][rg]);
      }
}

// ---------------------------------------------------------------------------
// K5 (new): per (b,h) build M-slice = Wp[:, h*48:+48] @ P_h  (192x48, bf16)
// where P_h = softmax(G * rq*rk*temp). M is the fused (proj @ blockdiag(P)).
// ---------------------------------------------------------------------------
__global__ __launch_bounds__(256) void k_mk(
    const float* __restrict__ G, const float* __restrict__ ssq_q,
    const float* __restrict__ ssq_k, const float* __restrict__ temp,
    const float* __restrict__ wp, u16* __restrict__ Mout)
{
  __shared__ u16 Pt[48 * 72];     // P^T rows d, cols c (pad 48->72, zeros)
  __shared__ u16 wA[192 * 72];    // Wp head-slice rows o, cols c (pad zeros)
  __shared__ float rks[48];
  int tid = threadIdx.x;
  int h = blockIdx.x, b = blockIdx.y;
  {
    s16x8 z = {};
    #pragma unroll
    for (int i = 0; i < 2; ++i){
      int idx = (i * 256 + tid) * 8;
      if (idx < 48 * 72) *(s16x8*)(&Pt[idx]) = z;
    }
    #pragma unroll
    for (int i = 0; i < 7; ++i){
      int idx = (i * 256 + tid) * 8;
      if (idx < 192 * 72) *(s16x8*)(&wA[idx]) = z;
    }
  }
  if (tid < DHEAD)
    rks[tid] = 1.f / fmaxf(sqrtf(ssq_k[b * CCH + h * DHEAD + tid]), 1e-12f);
  __syncthreads();
  if (tid < DHEAD){
    float rq = temp[h] / fmaxf(sqrtf(ssq_q[b * CCH + h * DHEAD + tid]), 1e-12f);
    const float* gr = G + (size_t)(b * NHEAD + h) * (DHEAD * DHEAD) + tid * DHEAD;
    float a[DHEAD];
    float mx = -1e30f;
    #pragma unroll
    for (int d = 0; d < DHEAD; ++d){
      a[d] = gr[d] * rq * rks[d];
      mx = fmaxf(mx, a[d]);
    }
    float sum = 0.f;
    #pragma unroll
    for (int d = 0; d < DHEAD; ++d){ a[d] = __expf(a[d] - mx); sum += a[d]; }
    float inv = 1.f / sum;
    #pragma unroll
    for (int d = 0; d < DHEAD; ++d) Pt[d * 72 + tid] = f2b(a[d] * inv);
  }
  // stage Wp head-slice bf16 (all threads; runs concurrent with softmax lanes)
  {
    const float* wb = wp + h * DHEAD;
    #pragma unroll
    for (int i = 0; i < 9; ++i){
      int e = (i * 256 + tid) * 4;       // 9216 = 192*48
      int row = e / DHEAD, col = e - row * DHEAD;
      float4 v = *(const float4*)(wb + (size_t)row * CCH + col);
      s16x4 pk;
      pk[0] = (short)f2b(v.x); pk[1] = (short)f2b(v.y);
      pk[2] = (short)f2b(v.z); pk[3] = (short)f2b(v.w);
      *(s16x4*)(&wA[row * 72 + col]) = pk;
    }
  }
  __syncthreads();
  int lane = tid & 63, wid = tid >> 6;
  int quad = lane >> 4, r = lane & 15;
  int wm = wid * 48;
  f32x4 acc[3][3] = {};
  #pragma unroll
  for (int ks = 0; ks < 2; ++ks){
    int k0 = ks * 32;
    bf16x8 af[3], bf[3];
    #pragma unroll
    for (int i = 0; i < 3; ++i)
      af[i] = *(const bf16x8*)(&wA[(wm + i * 16 + r) * 72 + k0 + quad * 8]);
    #pragma unroll
    for (int j = 0; j < 3; ++j)
      bf[j] = *(const bf16x8*)(&Pt[(j * 16 + r) * 72 + k0 + quad * 8]);
    #pragma unroll
    for (int i = 0; i < 3; ++i)
      #pragma unroll
      for (int j = 0; j < 3; ++j)
        acc[i][j] = __builtin_amdgcn_mfma_f32_16x16x32_bf16(af[i], bf[j], acc[i][j], 0, 0, 0);
  }
  u16* mb = Mout + (size_t)b * (CCH * CCH) + h * DHEAD;
  #pragma unroll
  for (int i = 0; i < 3; ++i)
    #pragma unroll
    for (int j = 0; j < 3; ++j)
      #pragma unroll
      for (int rg = 0; rg < 4; ++rg){
        int o = wm + i * 16 + quad * 4 + rg;
        int d = j * 16 + r;
        mb[(size_t)o * CCH + d] = f2b(acc[i][j][rg]);
      }
}

// ---------------------------------------------------------------------------
// K6 (new): fused attention+proj GEMM  Out[b][o][n] = sum_c M[b][o][c]*V[b][c][n]
// + resid.  V is in [c][n] plane layout; B-fragments built with
// ds_read_b64_tr_b16 from a 16x16-subtiled, row-permuted LDS staging
// (permutation m=((k>>3)<<2)|(k&3) so quad q receives k-rows 8q..8q+7).
// ---------------------------------------------------------------------------
__global__ __launch_bounds__(256) void k_gemmv(
    const u16* __restrict__ M, const u16* __restrict__ V,
    float* __restrict__ Out, const float* __restrict__ resid)
{
  __shared__ u16 lA[64 * 200];     // M slice rows
  __shared__ u16 lV[96 * 264];     // 6kb x 8nb x 2 tiles of 16x16 (+8 pad)
  int tid = threadIdx.x;
  int n0 = blockIdx.x * 128;
  int m0 = blockIdx.y * 64;
  int b  = blockIdx.z;
  {
    const u16* ap = M + (size_t)b * (CCH * CCH) + m0 * CCH;
    #pragma unroll
    for (int i = 0; i < 6; ++i){
      int off = (i * 256 + tid) * 8;
      int row = off / CCH, col = off - row * CCH;
      *(int4*)(&lA[row * 200 + col]) = *(const int4*)(ap + off);
    }
  }
  {
    const u16* vp = V + (size_t)b * CCH * HWSZ + n0;
    #pragma unroll
    for (int i = 0; i < 12; ++i){
      int e = i * 256 + tid;          // 3072 = 192c x 16 groups
      int c = e >> 4, ns = (e & 15) * 8;
      int4 v = *(const int4*)(vp + (size_t)c * HWSZ + ns);
      int kb = c >> 5, kr = c & 31;
      int tile = (kr >> 2) & 1;
      int mr = ((kr >> 3) << 2) | (kr & 3);
      int ti = (kb * 8 + (ns >> 4)) * 2 + tile;
      *(int4*)(&lV[ti * 264 + mr * 16 + (ns & 15)]) = v;
    }
  }
  __syncthreads();
  int lane = tid & 63, wid = tid >> 6;
  int quad = lane >> 4, r = lane & 15;
  int wm = (wid >> 1) * 32, wn = (wid & 1) * 64;
  unsigned lvb = (unsigned)(uintptr_t)(&lV[0]) + 2u * (unsigned)(r + quad * 64)
               + (unsigned)((wn >> 4) * 2) * 528u;
  f32x4 acc[2][4] = {};
  #pragma unroll
  for (int kb = 0; kb < 6; ++kb){
    int k0 = kb * 32;
    s16x4 lo[4], hi[4];
    #pragma unroll
    for (int j = 0; j < 4; ++j){
      unsigned a = lvb + (unsigned)kb * 8448u + (unsigned)j * 1056u;
      asm volatile("ds_read_b64_tr_b16 %0, %1" : "=&v"(lo[j]) : "v"(a));
      asm volatile("ds_read_b64_tr_b16 %0, %1 offset:528" : "=&v"(hi[j]) : "v"(a));
    }
    bf16x8 af[2];
    #pragma unroll
    for (int i = 0; i < 2; ++i)
      af[i] = *(const bf16x8*)(&lA[(wm + i * 16 + r) * 200 + k0 + quad * 8]);
    asm volatile("s_waitcnt lgkmcnt(0)" ::: "memory");
    __builtin_amdgcn_sched_barrier(0);
    #pragma unroll
    for (int j = 0; j < 4; ++j){
      union { s16x8 s; bf16x8 b; } u;
      u.s = __builtin_shufflevector(lo[j], hi[j], 0, 1, 2, 3, 4, 5, 6, 7);
      #pragma unroll
      for (int i = 0; i < 2; ++i)
        acc[i][j] = __builtin_amdgcn_mfma_f32_16x16x32_bf16(af[i], u.b, acc[i][j], 0, 0, 0);
    }
  }
  size_t obase = (size_t)b * CCH * HWSZ;
  #pragma unroll
  for (int i = 0; i < 2; ++i){
    #pragma unroll
    for (int rg = 0; rg < 4; ++rg){
      int o = m0 + wm + i * 16 + quad * 4 + rg;
      size_t rowb = obase + (size_t)o * HWSZ;
      #pragma unroll
      for (int j = 0; j < 4; ++j){
        int n = n0 + wn + j * 16 + r;
        Out[rowb + n] = acc[i][j][rg] + resid[rowb + n];
      }
    }
  }
}

// ---------------------------------------------------------------------------
extern "C" void kernel_launch(void* const* d_in, const int* in_sizes, int n_in,
                              void* d_out, int out_size, void* d_ws, size_t ws_size,
                              hipStream_t stream)
{
  const float* xx     = (const float*)d_in[0];
  const float* q_in   = (const float*)d_in[1];
  const float* ln_w   = (const float*)d_in[2];
  const float* ln_b   = (const float*)d_in[3];
  const float* w_q    = (const float*)d_in[4];
  const float* w_k    = (const float*)d_in[5];
  const float* w_v    = (const float*)d_in[6];
  const float* wd_q   = (const float*)d_in[7];
  const float* wd_k   = (const float*)d_in[8];
  const float* wd_v   = (const float*)d_in[9];
  const float* w_proj = (const float*)d_in[10];
  const float* temp   = (const float*)d_in[11];

  const size_t SZ = (size_t)NB * CCH * HWSZ;
  u16* B1 = (u16*)d_ws;                          // v_conv -> v_dw (in-place)
  u16* B2 = B1 + SZ;                             // k_conv -> k_dw (in-place)
  u16* B3 = B2 + SZ;                             // q_conv -> q_dw (in-place)
  float* G     = (float*)(B3 + SZ);
  float* ssq_q = G + 32 * DHEAD * DHEAD;
  float* ssq_k = ssq_q + NB * CCH;
  u16* Mb      = (u16*)(ssq_k + NB * CCH);       // fused proj matrices, 590 KB
  u16* lnbuf   = (u16*)d_out;                    // LN output scratch (overwritten later)

  hipMemsetAsync(G, 0, (size_t)(32 * DHEAD * DHEAD + 2 * NB * CCH) * sizeof(float), stream);

  dim3 gg(128, 3, NB);
  k_ln_t<<<NB * 256, 256, 0, stream>>>(xx, ln_w, ln_b, lnbuf);
  k_gemm<0><<<gg, 256, 0, stream>>>(w_k, lnbuf, B2, nullptr);
  k_gemm<0><<<gg, 256, 0, stream>>>(w_v, lnbuf, B1, nullptr);
  k_ln_t<<<NB * 256, 256, 0, stream>>>(q_in, ln_w, ln_b, lnbuf);
  k_gemm<0><<<gg, 256, 0, stream>>>(w_q, lnbuf, B3, nullptr);
  // merged depthwise: q in B3, k in B2, v in B1 — all in-place
  k_dw3<<<dim3(NB * CCH, 3), 256, 0, stream>>>(wd_q, wd_k, wd_v,
                                               B3, B2, B1, ssq_q, ssq_k);
  k_gram<<<dim3(16, NHEAD, NB), 256, 0, stream>>>(B3, B2, G);
  // fold softmax+proj into per-batch 192x192 matrix M
  k_mk<<<dim3(NHEAD, NB), 256, 0, stream>>>(G, ssq_q, ssq_k, temp, w_proj, Mb);
  // out = M @ V + q_in  (single fused GEMM, replaces attn@V and proj)
  k_gemmv<<<gg, 256, 0, stream>>>(Mb, B1, (float*)d_out, q_in);
}

// Round 3
// 433.550 us; speedup vs baseline: 1.5514x; 1.1025x over previous
//
#include <hip/hip_runtime.h>
#include <hip/hip_bf16.h>
#include <stdint.h>

#define HWSZ 16384
#define CCH 192
#define NB 8
#define NHEAD 4
#define DHEAD 48

typedef unsigned short u16;
typedef __bf16 bf16x8 __attribute__((ext_vector_type(8)));
typedef float f32x4 __attribute__((ext_vector_type(4)));
typedef short s16x8 __attribute__((ext_vector_type(8)));
typedef short s16x4 __attribute__((ext_vector_type(4)));

__device__ __forceinline__ float b2f(u16 h){
  union { unsigned u; float f; } v; v.u = ((unsigned)h) << 16; return v.f;
}
__device__ __forceinline__ u16 f2b(float f){
  union { float f; unsigned u; } v; v.f = f;
  unsigned r = v.u + 0x7fffu + ((v.u >> 16) & 1u);
  return (u16)(r >> 16);
}

// ---------------------------------------------------------------------------
// K0: pack w_q,w_k,w_v (f32 192x192) to bf16 once (L2-resident for k_lngemm).
// ---------------------------------------------------------------------------
__global__ __launch_bounds__(256) void k_wpack(
    const float* __restrict__ wq, const float* __restrict__ wk,
    const float* __restrict__ wv, u16* __restrict__ o)
{
  int m = blockIdx.x;
  const float* src = (m == 0) ? wq : (m == 1) ? wk : wv;
  u16* dst = o + (size_t)m * CCH * CCH;
  int tid = threadIdx.x;
  #pragma unroll
  for (int i = 0; i < 36; ++i){
    int e = (i * 256 + tid) * 4;
    float4 v = *(const float4*)(src + e);
    s16x4 pk;
    pk[0] = (short)f2b(v.x); pk[1] = (short)f2b(v.y);
    pk[2] = (short)f2b(v.z); pk[3] = (short)f2b(v.w);
    *(s16x4*)(dst + e) = pk;
  }
}

// ---------------------------------------------------------------------------
// K1: fused LayerNorm + conv1x1 GEMM(s).
// Per block: 64 px. LN over 192 ch in f32 -> bf16 tile in LDS -> GEMM against
// NG weight matrices (A-fragments streamed from L2-resident bf16 weights).
// Out[b][o][px] plane layout bf16 (same as old k_gemm<0> output).
// ---------------------------------------------------------------------------
template<int NG>
__global__ __launch_bounds__(256) void k_lngemm(
    const float* __restrict__ x, const float* __restrict__ lnw,
    const float* __restrict__ lnb,
    const u16* __restrict__ W0, const u16* __restrict__ W1,
    u16* __restrict__ O0, u16* __restrict__ O1)
{
  __shared__ float xs[CCH * 66];   // [c][px] f32 tile (50688 B)
  __shared__ float red[512];       // partials -> {mu, rstd, lw, lb}
  __shared__ u16 lnX[64 * 200];    // [px][c] bf16 tile (25600 B)
  int tid = threadIdx.x;
  int b   = blockIdx.y;
  int p0  = blockIdx.x * 64;

  float wl = 0.f, bl = 0.f;
  if (tid >= 64){
    int c = tid - 64;
    wl = lnw[c]; bl = lnb[c];
  }

  // Phase A: stage 192x64 f32 tile, 12 independent float4 per thread
  {
    const float* xb = x + (size_t)b * CCH * HWSZ + p0;
    int cq = tid >> 4;
    int q  = tid & 15;
    float4 v[12];
    #pragma unroll
    for (int i = 0; i < 12; ++i){
      int c = i * 16 + cq;
      v[i] = *(const float4*)(xb + (size_t)c * HWSZ + q * 4);
    }
    #pragma unroll
    for (int i = 0; i < 12; ++i){
      int c = i * 16 + cq;
      float* dst = &xs[c * 66 + q * 4];
      *(float2*)(dst)     = make_float2(v[i].x, v[i].y);
      *(float2*)(dst + 2) = make_float2(v[i].z, v[i].w);
    }
  }
  __syncthreads();

  // Phase B: parallel stats — wave w sums channels [48w, 48w+48), lane = px
  {
    int w = tid >> 6, l = tid & 63;
    float s = 0.f, ss = 0.f;
    #pragma unroll
    for (int j = 0; j < 48; ++j){
      float v = xs[(48 * w + j) * 66 + l];
      s += v; ss += v * v;
    }
    red[w * 64 + l]       = s;
    red[256 + w * 64 + l] = ss;
  }
  __syncthreads();

  float mu = 0.f, rs = 0.f;
  if (tid < 64){
    float s  = red[tid]       + red[64 + tid]  + red[128 + tid] + red[192 + tid];
    float ss = red[256 + tid] + red[320 + tid] + red[384 + tid] + red[448 + tid];
    mu = s * (1.f / CCH);
    float var = ss * (1.f / CCH) - mu * mu;
    rs = rsqrtf(var + 1e-5f);
  }
  __syncthreads();
  if (tid < 64){ red[tid] = mu; red[64 + tid] = rs; }
  else { int c = tid - 64; red[128 + c] = wl; red[320 + c] = bl; }
  __syncthreads();

  // Phase D: normalize -> bf16 LDS tile [px][200]
  {
    int px = tid >> 2;
    int cb = tid & 3;
    float m = red[px];
    float r = red[64 + px];
    #pragma unroll
    for (int i = 0; i < 6; ++i){
      int c0 = (cb + i * 4) * 8;
      s16x8 pk;
      #pragma unroll
      for (int j = 0; j < 8; ++j){
        int c = c0 + j;
        float o = (xs[c * 66 + px] - m) * r * red[128 + c] + red[320 + c];
        pk[j] = (short)f2b(o);
      }
      *(s16x8*)(&lnX[px * 200 + c0]) = pk;
    }
  }
  __syncthreads();

  // GEMM phase: wave owns M-rows [wid*48, +48) for each weight matrix.
  int lane = tid & 63, wid = tid >> 6;
  int quad = lane >> 4, r = lane & 15;
  int wm = wid * 48;
  const u16* A0 = W0 + (size_t)wm * CCH;
  const u16* A1 = (NG == 2) ? (W1 + (size_t)wm * CCH) : nullptr;
  f32x4 acc0[3][4] = {};
  f32x4 acc1[3][4] = {};
  #pragma unroll
  for (int ks = 0; ks < 6; ++ks){
    int k0 = ks * 32;
    bf16x8 bfv[4];
    #pragma unroll
    for (int j = 0; j < 4; ++j)
      bfv[j] = *(const bf16x8*)(&lnX[(j * 16 + r) * 200 + k0 + quad * 8]);
    bf16x8 a0[3], a1[3];
    #pragma unroll
    for (int i = 0; i < 3; ++i)
      a0[i] = *(const bf16x8*)(A0 + (size_t)(i * 16 + r) * CCH + k0 + quad * 8);
    if (NG == 2){
      #pragma unroll
      for (int i = 0; i < 3; ++i)
        a1[i] = *(const bf16x8*)(A1 + (size_t)(i * 16 + r) * CCH + k0 + quad * 8);
    }
    #pragma unroll
    for (int i = 0; i < 3; ++i)
      #pragma unroll
      for (int j = 0; j < 4; ++j)
        acc0[i][j] = __builtin_amdgcn_mfma_f32_16x16x32_bf16(a0[i], bfv[j], acc0[i][j], 0, 0, 0);
    if (NG == 2){
      #pragma unroll
      for (int i = 0; i < 3; ++i)
        #pragma unroll
        for (int j = 0; j < 4; ++j)
          acc1[i][j] = __builtin_amdgcn_mfma_f32_16x16x32_bf16(a1[i], bfv[j], acc1[i][j], 0, 0, 0);
    }
  }
  size_t ob = (size_t)b * CCH * HWSZ;
  #pragma unroll
  for (int i = 0; i < 3; ++i){
    #pragma unroll
    for (int rg = 0; rg < 4; ++rg){
      int o = wm + i * 16 + quad * 4 + rg;
      size_t rowb = ob + (size_t)o * HWSZ;
      #pragma unroll
      for (int j = 0; j < 4; ++j){
        int n = p0 + j * 16 + r;
        O0[rowb + n] = f2b(acc0[i][j][rg]);
        if (NG == 2) O1[rowb + n] = f2b(acc1[i][j][rg]);
      }
    }
  }
}

// ---------------------------------------------------------------------------
// K3: depthwise 3x3, register-rolling rewrite (no LDS, no bank conflicts).
// Thread = 8x8 px patch; loads rows y0-1..y0+8 to regs (10-deep ILP), one
// __syncthreads (vmcnt(0) drain) makes the in-place update race-free,
// halo px via __shfl_up/down. Each input row converted exactly once.
// ---------------------------------------------------------------------------
__global__ __launch_bounds__(256) void k_dw3(
    const float* __restrict__ wq, const float* __restrict__ wk,
    const float* __restrict__ wv,
    u16* __restrict__ bq, u16* __restrict__ bk, u16* __restrict__ bv,
    float* __restrict__ ssq_q, float* __restrict__ ssq_k)
{
  int tid = threadIdx.x;
  int bc  = blockIdx.x;                 // b*192 + c
  int z   = blockIdx.y;                 // 0=q 1=k 2=v
  int c   = bc % CCH;
  const float* wd = (z == 0) ? wq : (z == 1) ? wk : wv;
  u16* buf = (z == 0) ? bq : (z == 1) ? bk : bv;
  float w[9];
  #pragma unroll
  for (int t = 0; t < 9; ++t) w[t] = wd[c * 9 + t];
  u16* p = buf + (size_t)bc * HWSZ;

  int xseg = tid & 15, ygrp = tid >> 4;
  int x0 = xseg * 8, y0 = ygrp * 8;

  s16x8 zz = {0,0,0,0,0,0,0,0};
  s16x8 raw[10];
  #pragma unroll
  for (int rr = 0; rr < 10; ++rr){
    int yy = y0 - 1 + rr;
    raw[rr] = (yy >= 0 && yy < 128) ? *(const s16x8*)(p + yy * 128 + x0) : zz;
  }
  // __syncthreads drains vmcnt(0) first: all reads complete before any store.
  __syncthreads();

  float cf[10][8];
  float lf[10], rgt[10];
  #pragma unroll
  for (int rr = 0; rr < 10; ++rr){
    #pragma unroll
    for (int j = 0; j < 8; ++j) cf[rr][j] = b2f((u16)raw[rr][j]);
    float l  = __shfl_up(cf[rr][7], 1);
    float rr_ = __shfl_down(cf[rr][0], 1);
    lf[rr]  = (xseg > 0)  ? l   : 0.f;
    rgt[rr] = (xseg < 15) ? rr_ : 0.f;
  }

  float ss = 0.f;
  #pragma unroll
  for (int k = 0; k < 8; ++k){
    float acc[8] = {0.f,0.f,0.f,0.f,0.f,0.f,0.f,0.f};
    #pragma unroll
    for (int dy = 0; dy < 3; ++dy){
      int rr = k + dy;
      float wl = w[dy * 3], wc = w[dy * 3 + 1], wr = w[dy * 3 + 2];
      acc[0] += wl * lf[rr] + wc * cf[rr][0] + wr * cf[rr][1];
      #pragma unroll
      for (int j = 1; j < 7; ++j)
        acc[j] += wl * cf[rr][j - 1] + wc * cf[rr][j] + wr * cf[rr][j + 1];
      acc[7] += wl * cf[rr][6] + wc * cf[rr][7] + wr * rgt[rr];
    }
    s16x8 pk;
    #pragma unroll
    for (int j = 0; j < 8; ++j){
      pk[j] = (short)f2b(acc[j]);
      ss += acc[j] * acc[j];
    }
    *(s16x8*)(p + (y0 + k) * 128 + x0) = pk;
  }

  if (z < 2){
    #pragma unroll
    for (int m = 32; m > 0; m >>= 1) ss += __shfl_xor(ss, m);
    if ((tid & 63) == 0) atomicAdd(&((z == 0) ? ssq_q : ssq_k)[bc], ss);
  }
}

// ---------------------------------------------------------------------------
// K4: raw gram G[b][h][c][d] += sum_n q[c,n]*k[d,n], split-K (16 chunks),
// MFMA fragments straight from global; 4-wave LDS reduce then atomicAdd.
// ---------------------------------------------------------------------------
__global__ void k_gram(const u16* __restrict__ q, const u16* __restrict__ k,
                       float* __restrict__ G)
{
  __shared__ float gs[4 * 48 * 49];     // padded rows (49) to spread banks
  int tid = threadIdx.x;
  int chunk = blockIdx.x;
  int h = blockIdx.y, b = blockIdx.z;
  int lane = tid & 63, w = tid >> 6;
  int quad = lane >> 4, r = lane & 15;
  int nb = chunk * 1024 + w * 256;
  const u16* qb = q + ((size_t)b * CCH + h * DHEAD) * HWSZ;
  const u16* kb = k + ((size_t)b * CCH + h * DHEAD) * HWSZ;
  f32x4 acc[3][3] = {};
  for (int s = 0; s < 8; ++s){
    int kk = nb + s * 32 + quad * 8;
    bf16x8 af[3], bfr[3];
    #pragma unroll
    for (int i = 0; i < 3; ++i){
      af[i]  = *(const bf16x8*)(qb + (size_t)(i * 16 + r) * HWSZ + kk);
      bfr[i] = *(const bf16x8*)(kb + (size_t)(i * 16 + r) * HWSZ + kk);
    }
    #pragma unroll
    for (int i = 0; i < 3; ++i)
      #pragma unroll
      for (int j = 0; j < 3; ++j)
        acc[i][j] = __builtin_amdgcn_mfma_f32_16x16x32_bf16(af[i], bfr[j], acc[i][j], 0, 0, 0);
  }
  float* gw = gs + w * (48 * 49);
  #pragma unroll
  for (int i = 0; i < 3; ++i)
    #pragma unroll
    for (int j = 0; j < 3; ++j)
      #pragma unroll
      for (int rg = 0; rg < 4; ++rg){
        int row = i * 16 + quad * 4 + rg;
        int col = j * 16 + r;
        gw[row * 49 + col] = acc[i][j][rg];
      }
  __syncthreads();
  float* gb = G + (size_t)(b * NHEAD + h) * (DHEAD * DHEAD);
  #pragma unroll
  for (int t = 0; t < 9; ++t){
    int e = t * 256 + tid;              // 0..2303
    int row = e / 48, col = e - row * 48;
    int o = row * 49 + col;
    float s = gs[o] + gs[48 * 49 + o] + gs[2 * 48 * 49 + o] + gs[3 * 48 * 49 + o];
    atomicAdd(&gb[e], s);
  }
}

// ---------------------------------------------------------------------------
// K5: per (b,h) build M-slice = Wp[:, h*48:+48] @ P_h  (192x48, bf16)
// where P_h = softmax(G * rq*rk*temp). M is the fused (proj @ blockdiag(P)).
// ---------------------------------------------------------------------------
__global__ __launch_bounds__(256) void k_mk(
    const float* __restrict__ G, const float* __restrict__ ssq_q,
    const float* __restrict__ ssq_k, const float* __restrict__ temp,
    const float* __restrict__ wp, u16* __restrict__ Mout)
{
  __shared__ u16 Pt[48 * 72];     // P^T rows d, cols c (pad 48->72, zeros)
  __shared__ u16 wA[192 * 72];    // Wp head-slice rows o, cols c (pad zeros)
  __shared__ float rks[48];
  int tid = threadIdx.x;
  int h = blockIdx.x, b = blockIdx.y;
  {
    s16x8 z = {};
    #pragma unroll
    for (int i = 0; i < 2; ++i){
      int idx = (i * 256 + tid) * 8;
      if (idx < 48 * 72) *(s16x8*)(&Pt[idx]) = z;
    }
    #pragma unroll
    for (int i = 0; i < 7; ++i){
      int idx = (i * 256 + tid) * 8;
      if (idx < 192 * 72) *(s16x8*)(&wA[idx]) = z;
    }
  }
  if (tid < DHEAD)
    rks[tid] = 1.f / fmaxf(sqrtf(ssq_k[b * CCH + h * DHEAD + tid]), 1e-12f);
  __syncthreads();
  if (tid < DHEAD){
    float rq = temp[h] / fmaxf(sqrtf(ssq_q[b * CCH + h * DHEAD + tid]), 1e-12f);
    const float* gr = G + (size_t)(b * NHEAD + h) * (DHEAD * DHEAD) + tid * DHEAD;
    float a[DHEAD];
    float mx = -1e30f;
    #pragma unroll
    for (int d = 0; d < DHEAD; ++d){
      a[d] = gr[d] * rq * rks[d];
      mx = fmaxf(mx, a[d]);
    }
    float sum = 0.f;
    #pragma unroll
    for (int d = 0; d < DHEAD; ++d){ a[d] = __expf(a[d] - mx); sum += a[d]; }
    float inv = 1.f / sum;
    #pragma unroll
    for (int d = 0; d < DHEAD; ++d) Pt[d * 72 + tid] = f2b(a[d] * inv);
  }
  {
    const float* wb = wp + h * DHEAD;
    #pragma unroll
    for (int i = 0; i < 9; ++i){
      int e = (i * 256 + tid) * 4;       // 9216 = 192*48
      int row = e / DHEAD, col = e - row * DHEAD;
      float4 v = *(const float4*)(wb + (size_t)row * CCH + col);
      s16x4 pk;
      pk[0] = (short)f2b(v.x); pk[1] = (short)f2b(v.y);
      pk[2] = (short)f2b(v.z); pk[3] = (short)f2b(v.w);
      *(s16x4*)(&wA[row * 72 + col]) = pk;
    }
  }
  __syncthreads();
  int lane = tid & 63, wid = tid >> 6;
  int quad = lane >> 4, r = lane & 15;
  int wm = wid * 48;
  f32x4 acc[3][3] = {};
  #pragma unroll
  for (int ks = 0; ks < 2; ++ks){
    int k0 = ks * 32;
    bf16x8 af[3], bf[3];
    #pragma unroll
    for (int i = 0; i < 3; ++i)
      af[i] = *(const bf16x8*)(&wA[(wm + i * 16 + r) * 72 + k0 + quad * 8]);
    #pragma unroll
    for (int j = 0; j < 3; ++j)
      bf[j] = *(const bf16x8*)(&Pt[(j * 16 + r) * 72 + k0 + quad * 8]);
    #pragma unroll
    for (int i = 0; i < 3; ++i)
      #pragma unroll
      for (int j = 0; j < 3; ++j)
        acc[i][j] = __builtin_amdgcn_mfma_f32_16x16x32_bf16(af[i], bf[j], acc[i][j], 0, 0, 0);
  }
  u16* mb = Mout + (size_t)b * (CCH * CCH) + h * DHEAD;
  #pragma unroll
  for (int i = 0; i < 3; ++i)
    #pragma unroll
    for (int j = 0; j < 3; ++j)
      #pragma unroll
      for (int rg = 0; rg < 4; ++rg){
        int o = wm + i * 16 + quad * 4 + rg;
        int d = j * 16 + r;
        mb[(size_t)o * CCH + d] = f2b(acc[i][j][rg]);
      }
}

// ---------------------------------------------------------------------------
// K6: fused attention+proj GEMM  Out[b][o][n] = sum_c M[b][o][c]*V[b][c][n]
// + resid.  B-fragments via ds_read_b64_tr_b16 from 16x16-subtiled LDS.
// ---------------------------------------------------------------------------
__global__ __launch_bounds__(256) void k_gemmv(
    const u16* __restrict__ M, const u16* __restrict__ V,
    float* __restrict__ Out, const float* __restrict__ resid)
{
  __shared__ u16 lA[64 * 200];     // M slice rows
  __shared__ u16 lV[96 * 264];     // 6kb x 8nb x 2 tiles of 16x16 (+8 pad)
  int tid = threadIdx.x;
  int n0 = blockIdx.x * 128;
  int m0 = blockIdx.y * 64;
  int b  = blockIdx.z;
  {
    const u16* ap = M + (size_t)b * (CCH * CCH) + m0 * CCH;
    #pragma unroll
    for (int i = 0; i < 6; ++i){
      int off = (i * 256 + tid) * 8;
      int row = off / CCH, col = off - row * CCH;
      *(int4*)(&lA[row * 200 + col]) = *(const int4*)(ap + off);
    }
  }
  {
    const u16* vp = V + (size_t)b * CCH * HWSZ + n0;
    #pragma unroll
    for (int i = 0; i < 12; ++i){
      int e = i * 256 + tid;          // 3072 = 192c x 16 groups
      int c = e >> 4, ns = (e & 15) * 8;
      int4 v = *(const int4*)(vp + (size_t)c * HWSZ + ns);
      int kb = c >> 5, kr = c & 31;
      int tile = (kr >> 2) & 1;
      int mr = ((kr >> 3) << 2) | (kr & 3);
      int ti = (kb * 8 + (ns >> 4)) * 2 + tile;
      *(int4*)(&lV[ti * 264 + mr * 16 + (ns & 15)]) = v;
    }
  }
  __syncthreads();
  int lane = tid & 63, wid = tid >> 6;
  int quad = lane >> 4, r = lane & 15;
  int wm = (wid >> 1) * 32, wn = (wid & 1) * 64;
  unsigned lvb = (unsigned)(uintptr_t)(&lV[0]) + 2u * (unsigned)(r + quad * 64)
               + (unsigned)((wn >> 4) * 2) * 528u;
  f32x4 acc[2][4] = {};
  #pragma unroll
  for (int kb = 0; kb < 6; ++kb){
    int k0 = kb * 32;
    s16x4 lo[4], hi[4];
    #pragma unroll
    for (int j = 0; j < 4; ++j){
      unsigned a = lvb + (unsigned)kb * 8448u + (unsigned)j * 1056u;
      asm volatile("ds_read_b64_tr_b16 %0, %1" : "=&v"(lo[j]) : "v"(a));
      asm volatile("ds_read_b64_tr_b16 %0, %1 offset:528" : "=&v"(hi[j]) : "v"(a));
    }
    bf16x8 af[2];
    #pragma unroll
    for (int i = 0; i < 2; ++i)
      af[i] = *(const bf16x8*)(&lA[(wm + i * 16 + r) * 200 + k0 + quad * 8]);
    asm volatile("s_waitcnt lgkmcnt(0)" ::: "memory");
    __builtin_amdgcn_sched_barrier(0);
    #pragma unroll
    for (int j = 0; j < 4; ++j){
      union { s16x8 s; bf16x8 b; } u;
      u.s = __builtin_shufflevector(lo[j], hi[j], 0, 1, 2, 3, 4, 5, 6, 7);
      #pragma unroll
      for (int i = 0; i < 2; ++i)
        acc[i][j] = __builtin_amdgcn_mfma_f32_16x16x32_bf16(af[i], u.b, acc[i][j], 0, 0, 0);
    }
  }
  size_t obase = (size_t)b * CCH * HWSZ;
  #pragma unroll
  for (int i = 0; i < 2; ++i){
    #pragma unroll
    for (int rg = 0; rg < 4; ++rg){
      int o = m0 + wm + i * 16 + quad * 4 + rg;
      size_t rowb = obase + (size_t)o * HWSZ;
      #pragma unroll
      for (int j = 0; j < 4; ++j){
        int n = n0 + wn + j * 16 + r;
        Out[rowb + n] = acc[i][j][rg] + resid[rowb + n];
      }
    }
  }
}

// ---------------------------------------------------------------------------
extern "C" void kernel_launch(void* const* d_in, const int* in_sizes, int n_in,
                              void* d_out, int out_size, void* d_ws, size_t ws_size,
                              hipStream_t stream)
{
  const float* xx     = (const float*)d_in[0];
  const float* q_in   = (const float*)d_in[1];
  const float* ln_w   = (const float*)d_in[2];
  const float* ln_b   = (const float*)d_in[3];
  const float* w_q    = (const float*)d_in[4];
  const float* w_k    = (const float*)d_in[5];
  const float* w_v    = (const float*)d_in[6];
  const float* wd_q   = (const float*)d_in[7];
  const float* wd_k   = (const float*)d_in[8];
  const float* wd_v   = (const float*)d_in[9];
  const float* w_proj = (const float*)d_in[10];
  const float* temp   = (const float*)d_in[11];

  const size_t SZ = (size_t)NB * CCH * HWSZ;
  u16* B1 = (u16*)d_ws;                          // v_conv -> v_dw (in-place)
  u16* B2 = B1 + SZ;                             // k_conv -> k_dw (in-place)
  u16* B3 = B2 + SZ;                             // q_conv -> q_dw (in-place)
  float* G     = (float*)(B3 + SZ);
  float* ssq_q = G + 32 * DHEAD * DHEAD;
  float* ssq_k = ssq_q + NB * CCH;
  u16* Mb      = (u16*)(ssq_k + NB * CCH);       // fused proj matrices
  u16* Wb      = Mb + (size_t)NB * CCH * CCH;    // packed bf16 weights q,k,v

  hipMemsetAsync(G, 0, (size_t)(32 * DHEAD * DHEAD + 2 * NB * CCH) * sizeof(float), stream);

  k_wpack<<<3, 256, 0, stream>>>(w_q, w_k, w_v, Wb);
  // fused LN(xx) + {k,v} conv GEMMs; fused LN(q_in) + q conv GEMM
  k_lngemm<2><<<dim3(256, NB), 256, 0, stream>>>(
      xx, ln_w, ln_b, Wb + CCH * CCH, Wb + 2 * CCH * CCH, B2, B1);
  k_lngemm<1><<<dim3(256, NB), 256, 0, stream>>>(
      q_in, ln_w, ln_b, Wb, nullptr, B3, nullptr);
  // merged depthwise: q in B3, k in B2, v in B1 — all in-place
  k_dw3<<<dim3(NB * CCH, 3), 256, 0, stream>>>(wd_q, wd_k, wd_v,
                                               B3, B2, B1, ssq_q, ssq_k);
  k_gram<<<dim3(16, NHEAD, NB), 256, 0, stream>>>(B3, B2, G);
  // fold softmax+proj into per-batch 192x192 matrix M
  k_mk<<<dim3(NHEAD, NB), 256, 0, stream>>>(G, ssq_q, ssq_k, temp, w_proj, Mb);
  // out = M @ V + q_in  (single fused GEMM)
  k_gemmv<<<dim3(128, 3, NB), 256, 0, stream>>>(Mb, B1, (float*)d_out, q_in);
}